// Round 16
// baseline (401.012 us; speedup 1.0000x reference)
//
#include <hip/hip_runtime.h>
#include <hip/hip_bf16.h>

// IO-HMM fwd/bwd chain + projection for MI355X (gfx950).
// L=256 steps, B=128 batch, S=256 states, NL=64 labels.
//
// Kernel 1 (chain): R16 = BARRIERLESS SYSTOLIC RING. Evidence: step ~2050
//   cyc invariant to MFMA count (R12), LDS volume (R13/R14), wave count,
//   em prefetch depth (R15) => the cost is the barrier-lockstepped serial
//   phase train, not any pipe. Fix: drop s_barrier; wave u publishes
//   flag[u]=s (LDS, after lgkm drain) when its carry slice (states
//   [32u,32u+32) = k-slice kt=u) for step s is written. Each wave consumes
//   slices in ROTATED order starting at its own (kt = w, w+1, ...), gating
//   each slice on flag[u] >= s-1 with the next flag preloaded during the
//   current slice's MFMA -> waves run skewed, latencies overlap.
//   Safety: flags monotone (no deadlock); double buffer race-free: a step-
//   (s+2) overwrite is gated on all flags >= s+1, and flag s+1 is published
//   only after that wave finished ALL its step-(s+1) reads of the same
//   parity (program order + lgkmcnt(0) drain). Flags seeded to -1 before
//   the staging __syncthreads (stale-LDS hazard). A-frags loaded pre-
//   rotated (a_h[mt][j] <-> kt=(w+j)&7) so register indices stay constant.
//   Shape/precision = R13 (verified best): 16 blocks x 512 thr, 8 waves,
//   M=32/wave, single f16 T (absmax 128 = 0.64% vs 2% threshold), f16
//   carry plane, odd-8B stride 67 (0 conflicts), RNE packs (R8: RTZ bias
//   catastrophic), em distance-2 queue, fw/g stored f16.
// Kernel 2 (score): R11 version, untouched.

typedef _Float16 half8 __attribute__((ext_vector_type(8)));
typedef _Float16 half4 __attribute__((ext_vector_type(4)));
typedef float    f32x4 __attribute__((ext_vector_type(4)));
typedef unsigned long long u64;

#define LL 256
#define BB 128
#define SS 256
#define BT 16
#define RSTR8 67   // carry/p-plane row stride in 8B units (ODD -> conflict-free)
#define RSTRO 65   // o-plane row stride in 8B units (ODD -> conflict-free)

static __device__ __forceinline__ f32x4 mfma16f(half8 a, half8 b, f32x4 c) {
  return __builtin_amdgcn_mfma_f32_16x16x32_f16(a, b, c, 0, 0, 0);
}

// LDS-only barrier (score kernel): order ds ops, leave vmcnt in flight.
static __device__ __forceinline__ void lds_barrier() {
  __asm__ __volatile__("s_waitcnt lgkmcnt(0)\n\ts_barrier" ::: "memory");
}

// Drain LDS ops (no barrier) -- used before flag publish.
static __device__ __forceinline__ void lds_drain() {
  __asm__ __volatile__("s_waitcnt lgkmcnt(0)" ::: "memory");
}

// Round-to-nearest-even f16 pack (NOT cvt_pkrtz -- RTZ bias compounds over
// the 255-step chain into ~6% coherent shrink; R8 erratum).
static __device__ __forceinline__ u64 pack4(f32x4 v) {
  union { half4 h; u64 u; } x;
  x.h[0] = (_Float16)v[0];
  x.h[1] = (_Float16)v[1];
  x.h[2] = (_Float16)v[2];
  x.h[3] = (_Float16)v[3];
  return x.u;
}

// 16B logical fragment as two b64 reads (8B-aligned odd-stride layout).
static __device__ __forceinline__ half8 read_frag_s(const u64* plane, int row,
                                                    int kt, int q, int stride8) {
  const int o = row * stride8 + kt * 8 + q * 2;
  union { u64 u[2]; half8 v; } x;
  x.u[0] = plane[o];
  x.u[1] = plane[o + 1];
  return x.v;
}

__global__ __launch_bounds__(512, 2)
void hmm_chain(const int* __restrict__ sent, const float* __restrict__ emb,
               const float* __restrict__ T, _Float16* __restrict__ fwh,
               _Float16* __restrict__ gh)
{
  __shared__ u64 s_carry[2][BT * RSTR8]; // [buf][row*stride], single f16 plane
  __shared__ int s_tok[BT * 257];        // [batch][l], stride 257
  __shared__ int s_flag[8];              // flag[u] = last step wave u published

  const int tid  = threadIdx.x;
  const int lane = tid & 63;
  const int w    = tid >> 6;   // wave 0..7 -> states [32w, 32w+32) = kt slice w
  const int m    = lane & 15;  // A row-in-tile / B col (= batch)
  const int q    = lane >> 4;  // quad

  const int  bid = blockIdx.x;
  const bool fwd = (bid < 8);
  const int  bg0 = (fwd ? bid : bid - 8) * BT;
  _Float16* const obuf = fwd ? fwh : gh;
  volatile int* vflag = s_flag;

  // ---- seed flags to -1 (LDS may hold stale positive ints) ----
  if (tid < 8) s_flag[tid] = -1;

  // ---- stage sentence tokens ----
  for (int idx = tid; idx < BT * LL; idx += 512) {
    int bb = idx >> 8, l2 = idx & 255;
    s_tok[bb * 257 + l2] = sent[(bg0 + bb) * LL + l2];
  }
  __syncthreads();   // covers token staging AND flag seeding

  // ---- load T fragments PRE-ROTATED: a_h[mt][j] holds kt=(w+j)&7 ----
  half8 a_h[2][8];
#pragma unroll
  for (int mt = 0; mt < 2; ++mt) {
#pragma unroll
    for (int j = 0; j < 8; ++j) {
      const int kt = (w + j) & 7;
      const int r0 = 32 * w + 16 * mt + m;   // state (M index)
      const int kb = 32 * kt + 8 * q;        // k base
      float v[8];
      if (fwd) {
        f32x4 f0 = *(const f32x4*)(T + r0 * 256 + kb);
        f32x4 f1 = *(const f32x4*)(T + r0 * 256 + kb + 4);
#pragma unroll
        for (int jj = 0; jj < 4; ++jj) { v[jj] = f0[jj]; v[4 + jj] = f1[jj]; }
      } else {
#pragma unroll
        for (int jj = 0; jj < 8; ++jj) v[jj] = T[(kb + jj) * 256 + r0]; // T^T
      }
      half8 hi;
#pragma unroll
      for (int jj = 0; jj < 8; ++jj) hi[jj] = (_Float16)v[jj];   // RNE
      a_h[mt][j] = hi;
    }
  }

  // ---- init carry at l0 + first-row store; publish flag 0 ----
  const int l0 = fwd ? 0 : (LL - 1);
  {
    const int tok0 = s_tok[m * 257 + l0];
#pragma unroll
    for (int mt = 0; mt < 2; ++mt) {
      const int st = 32 * w + 16 * mt + 4 * q;
      f32x4 e0 = *(const f32x4*)(emb + (size_t)tok0 * 256 + st);
      u64 pc = pack4(e0);                       // carry = em[l0] both dirs
      f32x4 one = 1.0f;
      u64 po = fwd ? pc : pack4(one);           // g[L-1] = 1
      *(u64*)(obuf + (size_t)(l0 * BB + bg0 + m) * SS + st) = po;
      s_carry[0][m * RSTR8 + 8 * w + 4 * mt + q] = pc;
    }
  }
  lds_drain();
  if (lane == 0) vflag[w] = 0;

  // ---- em prefetch queue, distance 2 ----
  f32x4 em_q0[2], em_q1[2];
  {
    const int la = fwd ? 1 : (LL - 2);
    const int lb = fwd ? 2 : (LL - 3);
    const int ta = s_tok[m * 257 + la];
    const int tb = s_tok[m * 257 + lb];
#pragma unroll
    for (int mt = 0; mt < 2; ++mt) {
      em_q0[mt] = *(const f32x4*)(emb + (size_t)ta * 256 + 32 * w + 16 * mt + 4 * q);
      em_q1[mt] = *(const f32x4*)(emb + (size_t)tb * 256 + 32 * w + 16 * mt + 4 * q);
    }
  }

  // ---- main chain: barrierless systolic ring ----
  for (int s = 1; s < LL; ++s) {
    const int l    = fwd ? s : (LL - 1) - s;
    const int rb   = (s - 1) & 1, wb = s & 1;
    const int need = s - 1;

    const u64* pr = &s_carry[rb][0];

    f32x4 hh0 = 0.0f, hh1 = 0.0f;
    int fl_pre = 0;
#pragma unroll
    for (int j = 0; j < 8; ++j) {
      const int u = (w + j) & 7;
      if (j > 0) {                      // own slice (j=0) needs no gate
        int fl = fl_pre;
        while (fl < need) fl = vflag[u];
      }
      if (j < 7) fl_pre = vflag[(w + j + 1) & 7];   // preload next gate
      __asm__ __volatile__("" ::: "memory");        // pin reads after gate
      half8 bfr = read_frag_s(pr, m, u, q, RSTR8);
      hh0 = mfma16f(a_h[0][j], bfr, hh0);
      hh1 = mfma16f(a_h[1][j], bfr, hh1);
    }
    f32x4 v[2] = { hh0, hh1 };          // pre-em matmul result

    // rotate em queue; issue load for step s+2
    f32x4 em_now[2];
#pragma unroll
    for (int mt = 0; mt < 2; ++mt) { em_now[mt] = em_q0[mt]; em_q0[mt] = em_q1[mt]; }

    // epilogue: carry write, drain, publish flag, then global store + prefetch
    u64 sv[2];
#pragma unroll
    for (int mt = 0; mt < 2; ++mt) {
      f32x4 cn = v[mt] * em_now[mt];    // new carry
      u64 p0 = pack4(cn);
      s_carry[wb][m * RSTR8 + 8 * w + 4 * mt + q] = p0;
      sv[mt] = fwd ? p0 : pack4(v[mt]); // fwd stores fw[l]; bwd stores g[l]
    }
    lds_drain();
    if (lane == 0) vflag[w] = s;

#pragma unroll
    for (int mt = 0; mt < 2; ++mt) {
      const int st = 32 * w + 16 * mt + 4 * q;
      *(u64*)(obuf + (size_t)(l * BB + bg0 + m) * SS + st) = sv[mt];
    }
    {
      const int ln = fwd ? (s + 2 < LL ? s + 2 : LL - 1)
                         : ((LL - 3) - s > 0 ? (LL - 3) - s : 0);
      const int tokn = s_tok[m * 257 + ln];
#pragma unroll
      for (int mt = 0; mt < 2; ++mt)
        em_q1[mt] = *(const f32x4*)(emb + (size_t)tokn * 256 + 32 * w + 16 * mt + 4 * q);
    }
  }
}

__global__ __launch_bounds__(256, 2)
void hmm_score(const _Float16* __restrict__ fwh, const _Float16* __restrict__ gh,
               const float* __restrict__ outm, float* __restrict__ score)
{
  __shared__ u64 p_pl[64 * RSTR8];   // p = fw*g, [row][k] f16
  __shared__ u64 o_pl[64 * RSTRO];   // outm^T,   [n][k]  f16

  const int tid  = threadIdx.x;
  const int lane = tid & 63;
  const int w    = tid >> 6;
  const int rh   = w >> 1;     // row half: rows [32rh, 32rh+32)
  const int np   = w & 1;      // n-pair: n-tiles {2np, 2np+1}
  const int m    = lane & 15;
  const int q    = lane >> 4;
  const int R0   = blockIdx.x * 64;  // row = l*128 + b

  // ---- stage outm -> o_pl[n][k] f16 (RNE, hi only), coalesced f32x4 loads
  {
    _Float16* o_h = (_Float16*)o_pl;
    for (int i = tid; i < 4096; i += 256) {
      f32x4 v = *(const f32x4*)(outm + i * 4);   // flat = k*64+n
      int k = i >> 4, n0 = (i & 15) * 4;
#pragma unroll
      for (int r = 0; r < 4; ++r)
        o_h[(n0 + r) * (RSTRO * 4) + k] = (_Float16)v[r];
    }
  }

  // ---- stage p = fw * g (f16 packed mul, RNE) ----
  for (int idx = tid; idx < 64 * 64; idx += 256) {
    int row = idx >> 6, c = idx & 63;       // c = 8B column index
    union { u64 u; half4 h; } a, b, p;
    a.u = *(const u64*)(fwh + (size_t)(R0 + row) * 256 + c * 4);
    b.u = *(const u64*)(gh  + (size_t)(R0 + row) * 256 + c * 4);
    p.h = a.h * b.h;                        // v_pk_mul_f16 x2
    p_pl[row * RSTR8 + c] = p.u;
  }
  lds_barrier();

  f32x4 acc[2][2];
#pragma unroll
  for (int j = 0; j < 2; ++j)
#pragma unroll
    for (int jn = 0; jn < 2; ++jn) acc[j][jn] = 0.0f;

#pragma unroll
  for (int kt = 0; kt < 8; ++kt) {
    half8 of[2];
#pragma unroll
    for (int jn = 0; jn < 2; ++jn)
      of[jn] = read_frag_s(o_pl, 16 * (2 * np + jn) + m, kt, q, RSTRO);
#pragma unroll
    for (int j = 0; j < 2; ++j) {
      half8 pf = read_frag_s(p_pl, 32 * rh + 16 * j + m, kt, q, RSTR8);
#pragma unroll
      for (int jn = 0; jn < 2; ++jn)
        acc[j][jn] = mfma16f(pf, of[jn], acc[j][jn]);
    }
  }

#pragma unroll
  for (int j = 0; j < 2; ++j) {
#pragma unroll
    for (int jn = 0; jn < 2; ++jn) {
#pragma unroll
      for (int r = 0; r < 4; ++r) {
        int row = R0 + 32 * rh + 16 * j + 4 * q + r;
        int l = row >> 7, b = row & 127;
        score[(size_t)b * 16384 + l * 64 + 16 * (2 * np + jn) + m] = acc[j][jn][r];
      }
    }
  }
}

extern "C" void kernel_launch(void* const* d_in, const int* in_sizes, int n_in,
                              void* d_out, int out_size, void* d_ws, size_t ws_size,
                              hipStream_t stream) {
  (void)in_sizes; (void)n_in; (void)out_size; (void)ws_size;
  const int*   sent = (const int*)d_in[0];
  const float* emb  = (const float*)d_in[1];
  const float* T    = (const float*)d_in[2];
  const float* outm = (const float*)d_in[3];
  _Float16* fwh = (_Float16*)d_ws;                  // [L][B][S] f16, 16 MB
  _Float16* gh  = fwh + (size_t)LL * BB * SS;       // [L][B][S] f16, 16 MB

  hmm_chain<<<16, 512, 0, stream>>>(sent, emb, T, fwh, gh);
  hmm_score<<<512, 256, 0, stream>>>(fwh, gh, outm, (float*)d_out);
}

// Round 17
// 295.221 us; speedup vs baseline: 1.3583x; 1.3583x over previous
//
#include <hip/hip_runtime.h>
#include <hip/hip_bf16.h>

// IO-HMM fwd/bwd chain + projection for MI355X (gfx950).
// L=256 steps, B=128 batch, S=256 states, NL=64 labels.
//
// Kernel 1 (chain): R17 = R13 (proven best: 220 us) + TRUE distance-2 em
//   prefetch via 2-step unroll, no register copies.
//   Evidence: step ~2050 cyc invariant to MFMA count (R12), LDS volume
//   (R13/R14), wave count, and R16's barrierless ring regressed (flag
//   polls = LDS reads serialised into the MFMA loop). R15's "distance-2"
//   rotation em_q0=em_q1 COPIED the 1-iteration-old load, forcing the
//   vmcnt wait there -> slack stayed 1 step; the em-gather-latency theory
//   (scattered 64B rows from the 32MB emb table, L3/HBM ~600-900+ cyc,
//   spliced in at the pre-ds_write multiply each step) was never tested.
//   Here: unroll 2, sets em_a (odd steps) / em_b (even steps); a body
//   consumes its set (loaded 2 steps ago) in the epilogue, then reissues
//   the load into the SAME registers for step s+2 -> the only vmcnt wait
//   on the path is for a 2-step-old load.
//   Shape/precision = R13: 16 blocks x 512 thr, 8 waves, M=32/wave,
//   2 waves/SIMD; single f16 T (absmax 128 = 0.64% vs 2% threshold, RNE);
//   f16 carry LDS plane, double-buffered, odd-8B stride 67 (0 conflicts);
//   RNE packs (R8: RTZ bias -> 6% coherent shrink); lds-only barrier
//   (vmcnt in flight); fw/g stored f16.
// Kernel 2 (score): R11 version, untouched (gap ~75 us is harness
//   overhead, invariant across 7 score rewrites).

typedef _Float16 half8 __attribute__((ext_vector_type(8)));
typedef _Float16 half4 __attribute__((ext_vector_type(4)));
typedef float    f32x4 __attribute__((ext_vector_type(4)));
typedef unsigned long long u64;

#define LL 256
#define BB 128
#define SS 256
#define BT 16
#define RSTR8 67   // carry/p-plane row stride in 8B units (ODD -> conflict-free)
#define RSTRO 65   // o-plane row stride in 8B units (ODD -> conflict-free)

static __device__ __forceinline__ f32x4 mfma16f(half8 a, half8 b, f32x4 c) {
  return __builtin_amdgcn_mfma_f32_16x16x32_f16(a, b, c, 0, 0, 0);
}

// LDS-only barrier: order ds ops, leave vmcnt (global loads/stores) in flight.
static __device__ __forceinline__ void lds_barrier() {
  __asm__ __volatile__("s_waitcnt lgkmcnt(0)\n\ts_barrier" ::: "memory");
}

// Round-to-nearest-even f16 pack (NOT cvt_pkrtz -- RTZ bias compounds over
// the 255-step chain into ~6% coherent shrink; R8 erratum).
static __device__ __forceinline__ u64 pack4(f32x4 v) {
  union { half4 h; u64 u; } x;
  x.h[0] = (_Float16)v[0];
  x.h[1] = (_Float16)v[1];
  x.h[2] = (_Float16)v[2];
  x.h[3] = (_Float16)v[3];
  return x.u;
}

// 16B logical fragment as two b64 reads (8B-aligned odd-stride layout).
static __device__ __forceinline__ half8 read_frag_s(const u64* plane, int row,
                                                    int kt, int q, int stride8) {
  const int o = row * stride8 + kt * 8 + q * 2;
  union { u64 u[2]; half8 v; } x;
  x.u[0] = plane[o];
  x.u[1] = plane[o + 1];
  return x.v;
}

// One chain step at runtime step s, compile-time read-buffer parity RB.
// Consumes EM (loaded at step s-2); after consumption, reloads EM for s+2.
#define CHAIN_BODY(RB, EM)                                                     \
  {                                                                            \
    const u64* pr = &s_carry[RB][0];                                           \
    half8 bfr[8];                                                              \
    _Pragma("unroll")                                                          \
    for (int kt = 0; kt < 8; ++kt) bfr[kt] = read_frag_s(pr, m, kt, q, RSTR8); \
    f32x4 hh0 = 0.0f, hh1 = 0.0f;                                              \
    _Pragma("unroll")                                                          \
    for (int kt = 0; kt < 8; ++kt) {                                           \
      hh0 = mfma16f(a_h[0][kt], bfr[kt], hh0);                                 \
      hh1 = mfma16f(a_h[1][kt], bfr[kt], hh1);                                 \
    }                                                                          \
    const int l = fwd ? s : (LL - 1) - s;                                      \
    f32x4 c0 = hh0 * EM[0];   /* vmcnt wait: load is 2 steps old */            \
    f32x4 c1 = hh1 * EM[1];                                                    \
    u64 p0 = pack4(c0), p1 = pack4(c1);                                        \
    s_carry[RB ^ 1][m * RSTR8 + 8 * w + q]     = p0;                           \
    s_carry[RB ^ 1][m * RSTR8 + 8 * w + 4 + q] = p1;                           \
    u64 sv0 = fwd ? p0 : pack4(hh0);                                           \
    u64 sv1 = fwd ? p1 : pack4(hh1);                                           \
    { /* reload EM for step s+2 (true distance-2, no copies) */                \
      const int ln = fwd ? (s + 2 < LL ? s + 2 : LL - 1)                       \
                         : ((LL - 3) - s > 0 ? (LL - 3) - s : 0);              \
      const int tokn = s_tok[m * 257 + ln];                                    \
      EM[0] = *(const f32x4*)(emb + (size_t)tokn * 256 + 32 * w + 4 * q);      \
      EM[1] = *(const f32x4*)(emb + (size_t)tokn * 256 + 32 * w + 16 + 4 * q); \
    }                                                                          \
    *(u64*)(obuf + (size_t)(l * BB + bg0 + m) * SS + 32 * w + 4 * q) = sv0;    \
    *(u64*)(obuf + (size_t)(l * BB + bg0 + m) * SS + 32 * w + 16 + 4 * q) = sv1;\
    lds_barrier();                                                             \
  }

__global__ __launch_bounds__(512, 2)
void hmm_chain(const int* __restrict__ sent, const float* __restrict__ emb,
               const float* __restrict__ T, _Float16* __restrict__ fwh,
               _Float16* __restrict__ gh)
{
  __shared__ u64 s_carry[2][BT * RSTR8]; // [buf][row*stride], single f16 plane
  __shared__ int s_tok[BT * 257];        // [batch][l], stride 257

  const int tid  = threadIdx.x;
  const int lane = tid & 63;
  const int w    = tid >> 6;   // wave 0..7 -> states [32w, 32w+32)
  const int m    = lane & 15;  // A row-in-tile / B col (= batch)
  const int q    = lane >> 4;  // quad

  const int  bid = blockIdx.x;
  const bool fwd = (bid < 8);
  const int  bg0 = (fwd ? bid : bid - 8) * BT;
  _Float16* const obuf = fwd ? fwh : gh;

  // ---- stage sentence tokens ----
  for (int idx = tid; idx < BT * LL; idx += 512) {
    int bb = idx >> 8, l2 = idx & 255;
    s_tok[bb * 257 + l2] = sent[(bg0 + bb) * LL + l2];
  }
  __syncthreads();

  // ---- load T fragments (A operand), single f16: 16 frags = 64 regs
  half8 a_h[2][8];
#pragma unroll
  for (int mt = 0; mt < 2; ++mt) {
#pragma unroll
    for (int kt = 0; kt < 8; ++kt) {
      const int r0 = 32 * w + 16 * mt + m;   // state (M index)
      const int kb = 32 * kt + 8 * q;        // k base
      float v[8];
      if (fwd) {
        f32x4 f0 = *(const f32x4*)(T + r0 * 256 + kb);
        f32x4 f1 = *(const f32x4*)(T + r0 * 256 + kb + 4);
#pragma unroll
        for (int j = 0; j < 4; ++j) { v[j] = f0[j]; v[4 + j] = f1[j]; }
      } else {
#pragma unroll
        for (int j = 0; j < 8; ++j) v[j] = T[(kb + j) * 256 + r0]; // T^T
      }
      half8 hi;
#pragma unroll
      for (int j = 0; j < 8; ++j) hi[j] = (_Float16)v[j];   // RNE
      a_h[mt][kt] = hi;
    }
  }

  // ---- init carry at l0 + first-row store ----
  const int l0 = fwd ? 0 : (LL - 1);
  {
    const int tok0 = s_tok[m * 257 + l0];
#pragma unroll
    for (int mt = 0; mt < 2; ++mt) {
      const int st = 32 * w + 16 * mt + 4 * q;
      f32x4 e0 = *(const f32x4*)(emb + (size_t)tok0 * 256 + st);
      u64 pc = pack4(e0);                       // carry = em[l0] both dirs
      f32x4 one = 1.0f;
      u64 po = fwd ? pc : pack4(one);           // g[L-1] = 1
      *(u64*)(obuf + (size_t)(l0 * BB + bg0 + m) * SS + st) = po;
      s_carry[0][m * RSTR8 + 8 * w + 4 * mt + q] = pc;
    }
  }

  // ---- em sets: em_a for step 1 (and odd steps), em_b for step 2 (even)
  f32x4 em_a[2], em_b[2];
  {
    const int la = fwd ? 1 : (LL - 2);
    const int lb = fwd ? 2 : (LL - 3);
    const int ta = s_tok[m * 257 + la];
    const int tb = s_tok[m * 257 + lb];
#pragma unroll
    for (int mt = 0; mt < 2; ++mt) {
      em_a[mt] = *(const f32x4*)(emb + (size_t)ta * 256 + 32 * w + 16 * mt + 4 * q);
      em_b[mt] = *(const f32x4*)(emb + (size_t)tb * 256 + 32 * w + 16 * mt + 4 * q);
    }
  }
  __syncthreads();

  // ---- main chain: peeled s=1, then 127 pairs (s=2..255) ----
  int s = 1;
  CHAIN_BODY(0, em_a)          // s=1: reads buf0, writes buf1; reloads em_a for s=3
  ++s;
  for (int sp = 0; sp < 127; ++sp) {
    CHAIN_BODY(1, em_b)        // even s: reads buf1, writes buf0
    ++s;
    CHAIN_BODY(0, em_a)        // odd s: reads buf0, writes buf1
    ++s;
  }
}

__global__ __launch_bounds__(256, 2)
void hmm_score(const _Float16* __restrict__ fwh, const _Float16* __restrict__ gh,
               const float* __restrict__ outm, float* __restrict__ score)
{
  __shared__ u64 p_pl[64 * RSTR8];   // p = fw*g, [row][k] f16
  __shared__ u64 o_pl[64 * RSTRO];   // outm^T,   [n][k]  f16

  const int tid  = threadIdx.x;
  const int lane = tid & 63;
  const int w    = tid >> 6;
  const int rh   = w >> 1;     // row half: rows [32rh, 32rh+32)
  const int np   = w & 1;      // n-pair: n-tiles {2np, 2np+1}
  const int m    = lane & 15;
  const int q    = lane >> 4;
  const int R0   = blockIdx.x * 64;  // row = l*128 + b

  // ---- stage outm -> o_pl[n][k] f16 (RNE, hi only), coalesced f32x4 loads
  {
    _Float16* o_h = (_Float16*)o_pl;
    for (int i = tid; i < 4096; i += 256) {
      f32x4 v = *(const f32x4*)(outm + i * 4);   // flat = k*64+n
      int k = i >> 4, n0 = (i & 15) * 4;
#pragma unroll
      for (int r = 0; r < 4; ++r)
        o_h[(n0 + r) * (RSTRO * 4) + k] = (_Float16)v[r];
    }
  }

  // ---- stage p = fw * g (f16 packed mul, RNE) ----
  for (int idx = tid; idx < 64 * 64; idx += 256) {
    int row = idx >> 6, c = idx & 63;       // c = 8B column index
    union { u64 u; half4 h; } a, b, p;
    a.u = *(const u64*)(fwh + (size_t)(R0 + row) * 256 + c * 4);
    b.u = *(const u64*)(gh  + (size_t)(R0 + row) * 256 + c * 4);
    p.h = a.h * b.h;                        // v_pk_mul_f16 x2
    p_pl[row * RSTR8 + c] = p.u;
  }
  lds_barrier();

  f32x4 acc[2][2];
#pragma unroll
  for (int j = 0; j < 2; ++j)
#pragma unroll
    for (int jn = 0; jn < 2; ++jn) acc[j][jn] = 0.0f;

#pragma unroll
  for (int kt = 0; kt < 8; ++kt) {
    half8 of[2];
#pragma unroll
    for (int jn = 0; jn < 2; ++jn)
      of[jn] = read_frag_s(o_pl, 16 * (2 * np + jn) + m, kt, q, RSTRO);
#pragma unroll
    for (int j = 0; j < 2; ++j) {
      half8 pf = read_frag_s(p_pl, 32 * rh + 16 * j + m, kt, q, RSTR8);
#pragma unroll
      for (int jn = 0; jn < 2; ++jn)
        acc[j][jn] = mfma16f(pf, of[jn], acc[j][jn]);
    }
  }

#pragma unroll
  for (int j = 0; j < 2; ++j) {
#pragma unroll
    for (int jn = 0; jn < 2; ++jn) {
#pragma unroll
      for (int r = 0; r < 4; ++r) {
        int row = R0 + 32 * rh + 16 * j + 4 * q + r;
        int l = row >> 7, b = row & 127;
        score[(size_t)b * 16384 + l * 64 + 16 * (2 * np + jn) + m] = acc[j][jn][r];
      }
    }
  }
}

extern "C" void kernel_launch(void* const* d_in, const int* in_sizes, int n_in,
                              void* d_out, int out_size, void* d_ws, size_t ws_size,
                              hipStream_t stream) {
  (void)in_sizes; (void)n_in; (void)out_size; (void)ws_size;
  const int*   sent = (const int*)d_in[0];
  const float* emb  = (const float*)d_in[1];
  const float* T    = (const float*)d_in[2];
  const float* outm = (const float*)d_in[3];
  _Float16* fwh = (_Float16*)d_ws;                  // [L][B][S] f16, 16 MB
  _Float16* gh  = fwh + (size_t)LL * BB * SS;       // [L][B][S] f16, 16 MB

  hmm_chain<<<16, 512, 0, stream>>>(sent, emb, T, fwh, gh);
  hmm_score<<<512, 256, 0, stream>>>(fwh, gh, outm, (float*)d_out);
}